// Round 3
// baseline (1268.465 us; speedup 1.0000x reference)
//
#include <hip/hip_runtime.h>
#include <hip/hip_fp16.h>
#include <cstdint>
#include <cstddef>

#define B_N 65536
#define H_N 1024
#define S_N 1024
#define D_N 128

typedef __attribute__((ext_vector_type(8))) short bf16x8;
typedef __attribute__((ext_vector_type(8))) _Float16 f16x8;
typedef __attribute__((ext_vector_type(4))) float f32x4;

#define MFMA_BF(a, b, c) __builtin_amdgcn_mfma_f32_16x16x32_bf16((a), (b), (c), 0, 0, 0)
#define MFMA_F16(a, b, c) __builtin_amdgcn_mfma_f32_16x16x32_f16((a), (b), (c), 0, 0, 0)

__device__ __forceinline__ unsigned short f2bf(float f) {
    unsigned u = __float_as_uint(f);
    u += 0x7FFFu + ((u >> 16) & 1u);   // RNE
    return (unsigned short)(u >> 16);
}
__device__ __forceinline__ float h2f(unsigned short h) {
    return __half2float(__ushort_as_half(h));
}
__device__ __forceinline__ unsigned short f2h(float f) {
    return __half_as_ushort(__float2half_rn(f));
}
// async global->LDS, 16B/lane. LDS dest = wave-uniform base + lane*16.
__device__ __forceinline__ void async16(void* lds, const void* g) {
    __builtin_amdgcn_global_load_lds(
        (const __attribute__((address_space(1))) unsigned int*)g,
        (__attribute__((address_space(3))) unsigned int*)lds, 16, 0, 0);
}

// ---------------- zero csum ----------------
__global__ void k_zero(float* p, int n) {
    int i = blockIdx.x * blockDim.x + threadIdx.x;
    if (i < n) p[i] = 0.f;
}

// ---------------- query fp32 -> bf16, row-major ----------------
__global__ __launch_bounds__(256) void k_prep_q(const float* __restrict__ q,
                                                unsigned short* __restrict__ qb) {
    size_t i = ((size_t)blockIdx.x * 256 + threadIdx.x) * 8;
    float4 a = *(const float4*)(q + i);
    float4 b = *(const float4*)(q + i + 4);
    uint4 o;
    o.x = (unsigned)f2bf(a.x) | ((unsigned)f2bf(a.y) << 16);
    o.y = (unsigned)f2bf(a.z) | ((unsigned)f2bf(a.w) << 16);
    o.z = (unsigned)f2bf(b.x) | ((unsigned)f2bf(b.y) << 16);
    o.w = (unsigned)f2bf(b.z) | ((unsigned)f2bf(b.w) << 16);
    *(uint4*)(qb + i) = o;
}

// ---------------- W transpose+convert: wcat[n][k] bf16, n in [0,2048) ----------------
__global__ __launch_bounds__(256) void k_prep_w(const float* __restrict__ Wr,
                                                const float* __restrict__ Ww,
                                                unsigned short* __restrict__ wcat) {
    __shared__ float t[32][33];
    const int kb = blockIdx.x * 32, nb = blockIdx.y * 32;
    const float* src = blockIdx.z ? Ww : Wr;
    const int tx = threadIdx.x & 31, ty = threadIdx.x >> 5;
#pragma unroll
    for (int i = 0; i < 4; i++) {
        int r = ty + i * 8;
        t[r][tx] = src[(size_t)(kb + r) * S_N + nb + tx];
    }
    __syncthreads();
    unsigned short* dst = wcat + (size_t)blockIdx.z * 1024 * 1024;
#pragma unroll
    for (int i = 0; i < 4; i++) {
        int r = ty + i * 8;
        dst[(size_t)(nb + r) * 1024 + kb + tx] = f2bf(t[tx][r]);
    }
}

// ---------------- memory transpose: memT[d][s] fp16 ----------------
__global__ __launch_bounds__(256) void k_prep_mem(const float* __restrict__ mem,
                                                  unsigned short* __restrict__ memT) {
    __shared__ float t[32][33];
    const int db = blockIdx.x * 32, sb = blockIdx.y * 32;
    const int tx = threadIdx.x & 31, ty = threadIdx.x >> 5;
#pragma unroll
    for (int i = 0; i < 4; i++) {
        int r = ty + i * 8;
        t[r][tx] = mem[(size_t)(sb + r) * D_N + db + tx];
    }
    __syncthreads();
#pragma unroll
    for (int i = 0; i < 4; i++) {
        int r = ty + i * 8;
        memT[(size_t)(db + r) * 1024 + sb + tx] = f2h(t[tx][r]);
    }
}

// ---------------- content column-sum over B ----------------
__global__ __launch_bounds__(256) void k_content(const float* __restrict__ content,
                                                 float* __restrict__ csum) {
    const int tid = threadIdx.x;
    const size_t r0 = (size_t)blockIdx.x * 128;
    float4 a = {0.f, 0.f, 0.f, 0.f};
    const float* base = content + r0 * H_N + tid * 4;
#pragma unroll 8
    for (int r = 0; r < 128; r++) {
        float4 v = *(const float4*)(base + (size_t)r * H_N);
        a.x += v.x; a.y += v.y; a.z += v.z; a.w += v.w;
    }
    atomicAdd(&csum[tid * 4 + 0], a.x);
    atomicAdd(&csum[tid * 4 + 1], a.y);
    atomicAdd(&csum[tid * 4 + 2], a.z);
    atomicAdd(&csum[tid * 4 + 3], a.w);
}

// ---------------- main GEMM: e[rows][2048] = exp(Q @ [Wr|Ww] + bias) fp16 ----------------
// 1D grid (rows/128)*16, XCD-remapped so all 16 nb of one mb share an XCD.
// 256 thr = 4 waves, wave tile 64x64. Epilogue also emits per-block row sums.
__global__ __launch_bounds__(256) void k_gemm(const unsigned short* __restrict__ qb,
                                              const unsigned short* __restrict__ wcat,
                                              const float* __restrict__ b_read,
                                              const float* __restrict__ b_write,
                                              unsigned short* __restrict__ logits,
                                              float* __restrict__ wrp, int rowoff) {
    __shared__ unsigned short aL[4096];   // 128x32 bf16, XOR-swizzled 16B slots
    __shared__ unsigned short bL[4096];
    __shared__ float zb[2][128];
    const int tid = threadIdx.x;
    const int wave = tid >> 6, lane = tid & 63;
    const int wm = wave >> 1, wn = wave & 1;
    const int l16 = lane & 15, g = lane >> 4;
    // XCD remap: xcd = F&7 sees mb = xcd+8j, with nb cycling fastest in time
    const int F = blockIdx.x;
    const int x8 = F & 7, q = F >> 3;
    const int nb = q & 15;
    const int mb = x8 + 8 * (q >> 4);
    const size_t mrow = (size_t)mb * 128;

    f32x4 acc[4][4];
#pragma unroll
    for (int i = 0; i < 4; i++)
#pragma unroll
        for (int j = 0; j < 4; j++) acc[i][j] = (f32x4){0.f, 0.f, 0.f, 0.f};

    // staging: slot p holds logical row a=p>>2, seg=(p&3)^((a>>1)&3)
    const int a0 = tid >> 2;
    const int s0 = ((tid & 3) ^ ((a0 >> 1) & 3)) * 8;
    const unsigned short* wbase = wcat + (size_t)nb * 128 * 1024;
    const unsigned short* srcA = qb + (mrow + a0) * 1024 + s0;
    const unsigned short* srcB = wbase + (size_t)a0 * 1024 + s0;

    for (int k0 = 0; k0 < 1024; k0 += 32) {
        __syncthreads();
        async16((char*)aL + wave * 1024, srcA + k0);
        async16((char*)aL + 4096 + wave * 1024, srcA + 64 * 1024 + k0);
        async16((char*)bL + wave * 1024, srcB + k0);
        async16((char*)bL + 4096 + wave * 1024, srcB + 64 * 1024 + k0);
        __syncthreads();

        bf16x8 af[4], bv[4];
#pragma unroll
        for (int mt = 0; mt < 4; mt++) {
            int m = wm * 64 + mt * 16 + l16;
            int phys = m * 4 + (g ^ ((m >> 1) & 3));
            af[mt] = *(const bf16x8*)&aL[phys * 8];
        }
#pragma unroll
        for (int nt = 0; nt < 4; nt++) {
            int n = wn * 64 + nt * 16 + l16;
            int phys = n * 4 + (g ^ ((n >> 1) & 3));
            bv[nt] = *(const bf16x8*)&bL[phys * 8];
        }
#pragma unroll
        for (int mt = 0; mt < 4; mt++)
#pragma unroll
            for (int nt = 0; nt < 4; nt++)
                acc[mt][nt] = MFMA_BF(af[mt], bv[nt], acc[mt][nt]);
    }

    const float* bias = (nb < 8) ? b_read : b_write;
    const int cadj = (nb < 8) ? nb * 128 : nb * 128 - 1024;
    float rs[4][4];
#pragma unroll
    for (int i = 0; i < 4; i++)
#pragma unroll
        for (int j = 0; j < 4; j++) rs[i][j] = 0.f;
#pragma unroll
    for (int nt = 0; nt < 4; nt++) {
        const int col = wn * 64 + nt * 16 + l16;
        const float bvv = bias[cadj + col];
#pragma unroll
        for (int mt = 0; mt < 4; mt++) {
            const int row = wm * 64 + mt * 16 + g * 4;
#pragma unroll
            for (int r = 0; r < 4; r++) {
                float e = __expf(acc[mt][nt][r] + bvv);   // |logit|<~4 -> no max needed
                rs[mt][r] += e;
                logits[(mrow + row + r) * 2048 + nb * 128 + col] = f2h(e);
            }
        }
    }
    // row partial sums: reduce over the 16 l16 lanes, then across wn waves
#pragma unroll
    for (int mt = 0; mt < 4; mt++)
#pragma unroll
        for (int r = 0; r < 4; r++) {
            float v = rs[mt][r];
            v += __shfl_xor(v, 1); v += __shfl_xor(v, 2);
            v += __shfl_xor(v, 4); v += __shfl_xor(v, 8);
            rs[mt][r] = v;
        }
    if (l16 == 0) {
#pragma unroll
        for (int mt = 0; mt < 4; mt++)
#pragma unroll
            for (int r = 0; r < 4; r++)
                zb[wn][wm * 64 + mt * 16 + g * 4 + r] = rs[mt][r];
    }
    __syncthreads();
    if (tid < 128)
        wrp[(size_t)nb * B_N + rowoff + mrow + tid] = zb[0][tid] + zb[1][tid];
}

// ---------------- row-sum reduce: 16 partials -> 1/Z (read & write halves) ----------------
__global__ __launch_bounds__(256) void k_rowz(const float* __restrict__ wrp,
                                              float* __restrict__ zinv, int rowoff) {
    const int row = rowoff + blockIdx.x * 256 + threadIdx.x;
    float sr = 0.f, sw = 0.f;
#pragma unroll
    for (int nb = 0; nb < 8; nb++) sr += wrp[(size_t)nb * B_N + row];
#pragma unroll
    for (int nb = 8; nb < 16; nb++) sw += wrp[(size_t)nb * B_N + row];
    zinv[row] = 1.f / sr;
    zinv[B_N + row] = 1.f / sw;
}

// ---------------- PV: out[r][:] = (e_read[r] @ memT^T) * invZr, no LDS ----------------
// 256 thr = 4 waves; wave = 16 rows x 128 cols.
__global__ __launch_bounds__(256) void k_read(const unsigned short* __restrict__ logits,
                                              const unsigned short* __restrict__ memT,
                                              const float* __restrict__ zr,
                                              float* __restrict__ out) {
    const int wave = threadIdx.x >> 6, lane = threadIdx.x & 63;
    const int l16 = lane & 15, g = lane >> 4;
    const int r0 = blockIdx.x * 64 + wave * 16;
    f32x4 acc[8];
#pragma unroll
    for (int i = 0; i < 8; i++) acc[i] = (f32x4){0.f, 0.f, 0.f, 0.f};
    const unsigned short* arow = logits + (size_t)(r0 + l16) * 2048;
    for (int k0 = 0; k0 < 1024; k0 += 32) {
        f16x8 a = *(const f16x8*)&arow[k0 + g * 8];
#pragma unroll
        for (int nt = 0; nt < 8; nt++) {
            f16x8 b = *(const f16x8*)&memT[(size_t)(nt * 16 + l16) * 1024 + k0 + g * 8];
            acc[nt] = MFMA_F16(a, b, acc[nt]);
        }
    }
#pragma unroll
    for (int rr = 0; rr < 4; rr++) {
        const int row = r0 + g * 4 + rr;
        const float iz = zr[row];
#pragma unroll
        for (int nt = 0; nt < 8; nt++)
            out[(size_t)row * D_N + nt * 16 + l16] = acc[nt][rr] * iz;
    }
}

// ---------------- write-half column partials over 256-row slabs ----------------
__global__ __launch_bounds__(256) void k_wcol(const unsigned short* __restrict__ logits,
                                              const float* __restrict__ zw,
                                              float* __restrict__ wpart, int slab0) {
    const int tid = threadIdx.x;
    const int r0 = blockIdx.x * 256;
    float c0 = 0.f, c1 = 0.f, c2 = 0.f, c3 = 0.f;
#pragma unroll 4
    for (int r = 0; r < 256; r++) {
        const float iz = zw[r0 + r];
        uint2 u = *(const uint2*)&logits[(size_t)(r0 + r) * 2048 + 1024 + tid * 4];
        c0 += h2f((unsigned short)(u.x & 0xffff)) * iz;
        c1 += h2f((unsigned short)(u.x >> 16)) * iz;
        c2 += h2f((unsigned short)(u.y & 0xffff)) * iz;
        c3 += h2f((unsigned short)(u.y >> 16)) * iz;
    }
    float4 o = {c0, c1, c2, c3};
    *(float4*)&wpart[(size_t)(slab0 + blockIdx.x) * 1024 + tid * 4] = o;
}

// ---------------- reduce 256 slab partials -> wsum ----------------
__global__ __launch_bounds__(256) void k_wreduce(const float* __restrict__ wpart,
                                                 float* __restrict__ wsum) {
    const int c = blockIdx.x * 256 + threadIdx.x;
    float s = 0.f;
    for (int i = 0; i < 256; i++) s += wpart[(size_t)i * 1024 + c];
    wsum[c] = s;
}

// ---------------- c_mean = (csum/B) @ W_content + b_content ----------------
__global__ void k_cmean(const float* __restrict__ csum, const float* __restrict__ Wc,
                        const float* __restrict__ bc, float* __restrict__ cmean) {
    const int d = blockIdx.x, t = threadIdx.x;
    float s = 0.f;
#pragma unroll
    for (int j = 0; j < 16; j++) {
        int h = j * 64 + t;
        s += csum[h] * Wc[h * D_N + d];
    }
#pragma unroll
    for (int o = 1; o < 64; o <<= 1) s += __shfl_xor(s, o);
    if (t == 0) cmean[d] = s * (1.0f / (float)B_N) + bc[d];
}

// ---------------- memory update + age ----------------
__global__ __launch_bounds__(256) void k_final(const float* __restrict__ memory,
                                               const float* __restrict__ age,
                                               const float* __restrict__ wsum,
                                               const float* __restrict__ cmean,
                                               float* __restrict__ out) {
    const int idx = blockIdx.x * 256 + threadIdx.x;
    const int s = idx >> 7, d = idx & 127;
    const float wm = wsum[s] * (1.0f / (float)B_N);
    const bool mask = wm > 0.01f;
    const float cons = 1.0f / (1.0f + __expf(-0.1f * age[s]));
    const float f = wm * cons;
    const float m = memory[idx];
    const float nm = mask ? ((1.0f - f) * m + f * cmean[d]) : m;
    out[(size_t)B_N * D_N + idx] = nm;
    if (d == 0) out[(size_t)B_N * D_N + (size_t)S_N * D_N + s] = age[s] + (mask ? 1.0f : 0.0f);
}

extern "C" void kernel_launch(void* const* d_in, const int* in_sizes, int n_in,
                              void* d_out, int out_size, void* d_ws, size_t ws_size,
                              hipStream_t stream) {
    const float* query    = (const float*)d_in[0];
    const float* content  = (const float*)d_in[1];
    const float* memory   = (const float*)d_in[2];
    const float* age      = (const float*)d_in[3];
    const float* W_read   = (const float*)d_in[4];
    const float* b_read   = (const float*)d_in[5];
    const float* W_write  = (const float*)d_in[6];
    const float* b_write  = (const float*)d_in[7];
    const float* W_cont   = (const float*)d_in[8];
    const float* b_cont   = (const float*)d_in[9];

    char* ws = (char*)d_ws;
    unsigned short* wcat = (unsigned short*)ws;                        // 4 MB [2048][1024] bf16
    unsigned short* memT = (unsigned short*)(ws + (4u << 20));         // 256 KB [128][1024] fp16
    float* csum  = (float*)(ws + (4u << 20) + (256u << 10));           // 4 KB
    float* wsum  = csum + 1024;                                        // 4 KB
    float* cmean = csum + 2048;                                        // 512 B
    float* wrp   = (float*)(ws + (5u << 20));                          // 4 MB [16][B_N]
    float* zinv  = (float*)(ws + (9u << 20));                          // 512 KB [2][B_N]
    float* wpart = (float*)(ws + (9u << 20) + (512u << 10));           // 1 MB [256][1024]
    char* dynbase = ws + (11u << 20);
    float* out = (float*)d_out;

    // per chunk row: 2 KB (qbf) + 4 KB (logits); chunk must be multiple of 1024
    long long avail = (long long)ws_size - (11ll << 20);
    long long maxrows = avail > 0 ? avail / 6144 : 0;
    int CB = (int)((maxrows / 1024) * 1024);
    if (CB > B_N) CB = B_N;
    if (CB < 1024) CB = 1024;
    unsigned short* qbf    = (unsigned short*)dynbase;
    unsigned short* logits = (unsigned short*)(dynbase + (size_t)CB * 2048);

    k_zero<<<4, 256, 0, stream>>>(csum, 1024);
    k_prep_w<<<dim3(32, 32, 2), 256, 0, stream>>>(W_read, W_write, wcat);
    k_prep_mem<<<dim3(4, 32), 256, 0, stream>>>(memory, memT);
    k_content<<<512, 256, 0, stream>>>(content, csum);

    for (int s0 = 0; s0 < B_N; s0 += CB) {
        int rows = B_N - s0;
        if (rows > CB) rows = CB;
        k_prep_q<<<rows / 2, 256, 0, stream>>>(query + (size_t)s0 * H_N, qbf);
        k_gemm<<<(rows / 128) * 16, 256, 0, stream>>>(qbf, wcat, b_read, b_write,
                                                      logits, wrp, s0);
        k_rowz<<<rows / 256, 256, 0, stream>>>(wrp, zinv, s0);
        k_read<<<rows / 64, 256, 0, stream>>>(logits, memT, zinv + s0,
                                              out + (size_t)s0 * D_N);
        k_wcol<<<rows / 256, 256, 0, stream>>>(logits, zinv + B_N + s0, wpart, s0 / 256);
    }
    k_wreduce<<<4, 256, 0, stream>>>(wpart, wsum);
    k_cmean<<<128, 64, 0, stream>>>(csum, W_cont, b_cont, cmean);
    k_final<<<512, 256, 0, stream>>>(memory, age, wsum, cmean, out);
}